// Round 5
// baseline (706.424 us; speedup 1.0000x reference)
//
#include <hip/hip_runtime.h>
#include <hip/hip_bf16.h>
#include <cmath>

// Problem dims (fixed): B=16, T=1024, IN=1024, H=1024
// M = B*T = 16384, K1 = 1024, N1 = 1024, K2 = 2048, N2 = 1024
//
// NUMERICS-REPLICATION ROUND: the np golden is f32 (proven by round 4:
// exact-f64 end-to-end still differs by exactly one spike flip). Its einsum
// goes through BLAS sgemm = sequential ascending-k f32 FMA chain per output
// element, + separate f32 bias add. Its scan is numpy f32: mul, add (separate
// roundings), v*(1-spike), alpha = exp(-logaddexp(lt,0)) in f32 with
// correctly-rounded f32 transcendentals (glibc). We mirror all of that.
// GEMM2 (smooth tanh path) stays bf16 MFMA: ~1.5e-3 error class.

typedef __attribute__((ext_vector_type(8))) __bf16 bf16x8;
typedef __attribute__((ext_vector_type(4))) __bf16 bf16x4;
typedef __attribute__((ext_vector_type(4))) float  f32x4;

#define LDT 40  // bf16 LDS pad (GEMM2)
#define LDF 36  // f32 LDS pad (GEMM1)

// ---------------------------------------------------------------------------
// GEMM1 (f32 FMA-chain): I[m,h] = fadd( fmaf-chain_{k=0..1023}(x[m,k],W[h,k]),
//                                       b_in[h] )
// Strictly ascending k, single f32 accumulator -> mirrors BLAS sgemm numerics.
// ---------------------------------------------------------------------------
__global__ __launch_bounds__(256)
void gemm1_f32chain_kernel(const float* __restrict__ X,
                           const float* __restrict__ W,
                           const float* __restrict__ bias,
                           float* __restrict__ I)
{
    __shared__ __align__(16) float sA[128][LDF];
    __shared__ __align__(16) float sB[128][LDF];

    const int tid  = threadIdx.x;
    const int bn   = blockIdx.x;      // 0..7
    const int bm   = blockIdx.y;      // 0..127
    const int row0 = bm * 128;
    const int col0 = bn * 128;
    const int tx   = tid & 15;
    const int ty   = tid >> 4;

    float acc[8][8];
    #pragma unroll
    for (int i = 0; i < 8; ++i)
        #pragma unroll
        for (int j = 0; j < 8; ++j)
            acc[i][j] = 0.0f;

    for (int k0 = 0; k0 < 1024; k0 += 32) {
        #pragma unroll
        for (int i = 0; i < 4; ++i) {
            int q  = tid + i * 256;   // 0..1023
            int r  = q >> 3;          // 0..127
            int c4 = (q & 7) * 4;     // 0..28
            *(f32x4*)&sA[r][c4] = *(const f32x4*)&X[(size_t)(row0 + r) * 1024 + k0 + c4];
            *(f32x4*)&sB[r][c4] = *(const f32x4*)&W[(size_t)(col0 + r) * 1024 + k0 + c4];
        }
        __syncthreads();

        // ascending k; each acc[i][j] is one sequential FMA chain
        #pragma unroll 4
        for (int kk = 0; kk < 32; ++kk) {
            float a[8], b[8];
            #pragma unroll
            for (int i = 0; i < 8; ++i) a[i] = sA[ty + 16 * i][kk];
            #pragma unroll
            for (int j = 0; j < 8; ++j) b[j] = sB[tx + 16 * j][kk];
            #pragma unroll
            for (int i = 0; i < 8; ++i)
                #pragma unroll
                for (int j = 0; j < 8; ++j)
                    acc[i][j] = fmaf(a[i], b[j], acc[i][j]);
        }
        __syncthreads();
    }

    #pragma unroll
    for (int i = 0; i < 8; ++i)
        #pragma unroll
        for (int j = 0; j < 8; ++j) {
            int rg = row0 + ty + 16 * i;
            int cg = col0 + tx + 16 * j;
            I[(size_t)rg * 1024 + cg] = __fadd_rn(acc[i][j], bias[cg]);
        }
}

// ---------------------------------------------------------------------------
// Scan, numpy-f32 mirror:
//   alpha = expf(-logaddexpf(lt, 0))   [CR f32 transcendentals via f64 libm]
//   v = fadd(fmul(alpha, v), I)        [separate roundings, no FMA]
//   spike = v > thr; v = fmul(v, 1 - spike)
// writes combined [B,T,2H] bf16 (GEMM2 input; smooth path tolerates bf16)
// ---------------------------------------------------------------------------
__global__ void hsru_scan_f32_kernel(const float* __restrict__ I,
                                     const float* __restrict__ leak,
                                     const float* __restrict__ thr,
                                     __bf16* __restrict__ comb)
{
    int g = blockIdx.x * blockDim.x + threadIdx.x;  // 0..16383
    int b = g >> 10;
    int h = g & 1023;

    float lt = leak[h];
    // npy_logaddexpf(lt, 0) = max(lt,0) + log1pf(expf(-|lt|)), all f32 steps.
    // glibc f32 transcendentals are correctly rounded -> reproduce each as
    // round-to-f32 of the f64 libm value.
    float e     = (float)exp(-(double)fabsf(lt));
    float l1    = (float)log1p((double)e);
    float sp    = __fadd_rn(fmaxf(lt, 0.0f), l1);
    float alpha = (float)exp(-(double)sp);
    float th    = thr[h];

    const float* Ip = I    + (size_t)b * (1024 * 1024) + h;
    __bf16*      cp = comb + (size_t)b * (1024 * 2048) + h;

    float v = 0.0f;
    #pragma unroll 4
    for (int t = 0; t < 1024; ++t) {
        float cur = Ip[(size_t)t * 1024];
        v = __fadd_rn(__fmul_rn(alpha, v), cur);
        float spike = (v > th) ? 1.0f : 0.0f;
        v = __fmul_rn(v, __fsub_rn(1.0f, spike));
        cp[(size_t)t * 2048]        = (__bf16)v;
        cp[(size_t)t * 2048 + 1024] = (__bf16)spike;
    }
}

// ---------------------------------------------------------------------------
// GEMM2: out = tanh(combined @ W_out^T + b_out), bf16 MFMA (smooth path).
// ---------------------------------------------------------------------------
__global__ __launch_bounds__(256)
void gemm2_kernel(const __bf16* __restrict__ A,
                  const float* __restrict__ W,
                  const float* __restrict__ bias,
                  float* __restrict__ O)
{
    __shared__ __align__(16) __bf16 sA[128][LDT];
    __shared__ __align__(16) __bf16 sB[128][LDT];

    const int tid  = threadIdx.x;
    const int bn   = blockIdx.x;
    const int bm   = blockIdx.y;
    const int row0 = bm * 128;
    const int col0 = bn * 128;

    const int lane = tid & 63;
    const int wid  = tid >> 6;
    const int wm   = (wid >> 1) * 64;
    const int wn   = (wid & 1) * 64;

    f32x4 acc[4][4];
    #pragma unroll
    for (int i = 0; i < 4; ++i)
        #pragma unroll
        for (int j = 0; j < 4; ++j)
            acc[i][j] = f32x4{0.f, 0.f, 0.f, 0.f};

    const int frow  = lane & 15;
    const int fkoff = (lane >> 4) * 8;

    for (int k0 = 0; k0 < 2048; k0 += 32) {
        #pragma unroll
        for (int i = 0; i < 2; ++i) {
            int q  = tid + i * 256;
            int r  = q >> 2;
            int c8 = (q & 3) * 8;
            *(bf16x8*)&sA[r][c8] = *(const bf16x8*)&A[(size_t)(row0 + r) * 2048 + k0 + c8];
        }
        #pragma unroll
        for (int i = 0; i < 4; ++i) {
            int q  = tid + i * 256;
            int r  = q >> 3;
            int c4 = (q & 7) * 4;
            const f32x4 vb = *(const f32x4*)&W[(size_t)(col0 + r) * 2048 + k0 + c4];
            bf16x4 bh;
            #pragma unroll
            for (int j = 0; j < 4; ++j) bh[j] = (__bf16)vb[j];
            *(bf16x4*)&sB[r][c4] = bh;
        }
        __syncthreads();

        bf16x8 a_f[4], b_f[4];
        #pragma unroll
        for (int f = 0; f < 4; ++f) {
            a_f[f] = *(const bf16x8*)&sA[wm + f * 16 + frow][fkoff];
            b_f[f] = *(const bf16x8*)&sB[wn + f * 16 + frow][fkoff];
        }
        #pragma unroll
        for (int fm = 0; fm < 4; ++fm)
            #pragma unroll
            for (int fn = 0; fn < 4; ++fn)
                acc[fm][fn] = __builtin_amdgcn_mfma_f32_16x16x32_bf16(a_f[fm], b_f[fn], acc[fm][fn], 0, 0, 0);
        __syncthreads();
    }

    const int crow = (lane >> 4) * 4;
    const int ccol = lane & 15;
    #pragma unroll
    for (int fm = 0; fm < 4; ++fm)
        #pragma unroll
        for (int fn = 0; fn < 4; ++fn)
            #pragma unroll
            for (int j = 0; j < 4; ++j) {
                int rg = row0 + wm + fm * 16 + crow + j;
                int cg = col0 + wn + fn * 16 + ccol;
                O[(size_t)rg * 1024 + cg] = tanhf(acc[fm][fn][j] + bias[cg]);
            }
}

// ---------------------------------------------------------------------------
extern "C" void kernel_launch(void* const* d_in, const int* in_sizes, int n_in,
                              void* d_out, int out_size, void* d_ws, size_t ws_size,
                              hipStream_t stream)
{
    const float* x     = (const float*)d_in[0];
    const float* W_in  = (const float*)d_in[1];
    const float* b_in  = (const float*)d_in[2];
    const float* leak  = (const float*)d_in[3];
    const float* thr   = (const float*)d_in[4];
    const float* W_out = (const float*)d_in[5];
    const float* b_out = (const float*)d_in[6];

    const size_t NEED = 64ull * 1024 * 1024;  // comb bf16 [16,1024,2048]
    if (ws_size < NEED) return;

    float*  out  = (float*)d_out;   // also I scratch
    __bf16* comb = (__bf16*)d_ws;

    dim3 grid(8, 128);

    gemm1_f32chain_kernel<<<grid, 256, 0, stream>>>(x, W_in, b_in, out);
    hsru_scan_f32_kernel<<<64, 256, 0, stream>>>(out, leak, thr, comb);
    gemm2_kernel<<<grid, 256, 0, stream>>>(comb, W_out, b_out, out);
}

// Round 6
// 654.771 us; speedup vs baseline: 1.0789x; 1.0789x over previous
//
#include <hip/hip_runtime.h>
#include <hip/hip_bf16.h>
#include <cmath>

// Problem dims (fixed): B=16, T=1024, IN=1024, H=1024
// M = B*T = 16384, K1 = 1024, N1 = 1024, K2 = 2048, N2 = 1024
//
// Numerics contract (validated round 5): GEMM1 must be a sequential
// ascending-k f32 FMA chain per output element + separate f32 bias add
// (mirrors the np golden's BLAS sgemm). Scan mirrors numpy f32 op-for-op.
// GEMM2 (smooth tanh) is bf16 MFMA.
// This round: gemm1 LDS reads vectorized to ds_read_b128 (4 k at a time) —
// FMA ORDER UNCHANGED (kk, then q ascending) — to unstall the VALU.

typedef __attribute__((ext_vector_type(8))) __bf16 bf16x8;
typedef __attribute__((ext_vector_type(4))) __bf16 bf16x4;
typedef __attribute__((ext_vector_type(4))) float  f32x4;

#define LDT 40  // bf16 LDS pad (GEMM2)
#define LDF 36  // f32 LDS pad (GEMM1): 144B row stride, 16B-aligned slots

// ---------------------------------------------------------------------------
// GEMM1 (f32 FMA-chain): I[m,h] = fadd( fmaf-chain_{k=0..1023}, b_in[h] )
// ---------------------------------------------------------------------------
__global__ __launch_bounds__(256)
void gemm1_f32chain_kernel(const float* __restrict__ X,
                           const float* __restrict__ W,
                           const float* __restrict__ bias,
                           float* __restrict__ I)
{
    __shared__ __align__(16) float sA[128][LDF];
    __shared__ __align__(16) float sB[128][LDF];

    const int tid  = threadIdx.x;
    const int bn   = blockIdx.x;      // 0..7
    const int bm   = blockIdx.y;      // 0..127
    const int row0 = bm * 128;
    const int col0 = bn * 128;
    const int tx   = tid & 15;
    const int ty   = tid >> 4;

    float acc[8][8];
    #pragma unroll
    for (int i = 0; i < 8; ++i)
        #pragma unroll
        for (int j = 0; j < 8; ++j)
            acc[i][j] = 0.0f;

    for (int k0 = 0; k0 < 1024; k0 += 32) {
        #pragma unroll
        for (int i = 0; i < 4; ++i) {
            int q  = tid + i * 256;   // 0..1023
            int r  = q >> 3;          // 0..127
            int c4 = (q & 7) * 4;     // 0..28
            *(f32x4*)&sA[r][c4] = *(const f32x4*)&X[(size_t)(row0 + r) * 1024 + k0 + c4];
            *(f32x4*)&sB[r][c4] = *(const f32x4*)&W[(size_t)(col0 + r) * 1024 + k0 + c4];
        }
        __syncthreads();

        // ds_read_b128: 4 consecutive k per row per read. FMA order is still
        // strictly ascending k (kk group ascending, q ascending within it).
        #pragma unroll
        for (int kk = 0; kk < 32; kk += 4) {
            f32x4 a4[8], b4[8];
            #pragma unroll
            for (int i = 0; i < 8; ++i) a4[i] = *(const f32x4*)&sA[ty + 16 * i][kk];
            #pragma unroll
            for (int j = 0; j < 8; ++j) b4[j] = *(const f32x4*)&sB[tx + 16 * j][kk];
            #pragma unroll
            for (int q = 0; q < 4; ++q)
                #pragma unroll
                for (int i = 0; i < 8; ++i)
                    #pragma unroll
                    for (int j = 0; j < 8; ++j)
                        acc[i][j] = fmaf(a4[i][q], b4[j][q], acc[i][j]);
        }
        __syncthreads();
    }

    #pragma unroll
    for (int i = 0; i < 8; ++i)
        #pragma unroll
        for (int j = 0; j < 8; ++j) {
            int rg = row0 + ty + 16 * i;
            int cg = col0 + tx + 16 * j;
            I[(size_t)rg * 1024 + cg] = __fadd_rn(acc[i][j], bias[cg]);
        }
}

// ---------------------------------------------------------------------------
// Scan, numpy-f32 mirror (validated):
//   alpha = expf(-logaddexpf(lt,0)) via round-to-f32 of f64 libm
//   v = fadd(fmul(alpha, v), I); spike = v > thr; v = fmul(v, 1-spike)
// ---------------------------------------------------------------------------
__global__ void hsru_scan_f32_kernel(const float* __restrict__ I,
                                     const float* __restrict__ leak,
                                     const float* __restrict__ thr,
                                     __bf16* __restrict__ comb)
{
    int g = blockIdx.x * blockDim.x + threadIdx.x;  // 0..16383
    int b = g >> 10;
    int h = g & 1023;

    float lt = leak[h];
    float e     = (float)exp(-(double)fabsf(lt));
    float l1    = (float)log1p((double)e);
    float sp    = __fadd_rn(fmaxf(lt, 0.0f), l1);
    float alpha = (float)exp(-(double)sp);
    float th    = thr[h];

    const float* Ip = I    + (size_t)b * (1024 * 1024) + h;
    __bf16*      cp = comb + (size_t)b * (1024 * 2048) + h;

    float v = 0.0f;
    #pragma unroll 4
    for (int t = 0; t < 1024; ++t) {
        float cur = Ip[(size_t)t * 1024];
        v = __fadd_rn(__fmul_rn(alpha, v), cur);
        float spike = (v > th) ? 1.0f : 0.0f;
        v = __fmul_rn(v, __fsub_rn(1.0f, spike));
        cp[(size_t)t * 2048]        = (__bf16)v;
        cp[(size_t)t * 2048 + 1024] = (__bf16)spike;
    }
}

// ---------------------------------------------------------------------------
// GEMM2: out = tanh(combined @ W_out^T + b_out), bf16 MFMA (smooth path).
// ---------------------------------------------------------------------------
__global__ __launch_bounds__(256)
void gemm2_kernel(const __bf16* __restrict__ A,
                  const float* __restrict__ W,
                  const float* __restrict__ bias,
                  float* __restrict__ O)
{
    __shared__ __align__(16) __bf16 sA[128][LDT];
    __shared__ __align__(16) __bf16 sB[128][LDT];

    const int tid  = threadIdx.x;
    const int bn   = blockIdx.x;
    const int bm   = blockIdx.y;
    const int row0 = bm * 128;
    const int col0 = bn * 128;

    const int lane = tid & 63;
    const int wid  = tid >> 6;
    const int wm   = (wid >> 1) * 64;
    const int wn   = (wid & 1) * 64;

    f32x4 acc[4][4];
    #pragma unroll
    for (int i = 0; i < 4; ++i)
        #pragma unroll
        for (int j = 0; j < 4; ++j)
            acc[i][j] = f32x4{0.f, 0.f, 0.f, 0.f};

    const int frow  = lane & 15;
    const int fkoff = (lane >> 4) * 8;

    for (int k0 = 0; k0 < 2048; k0 += 32) {
        #pragma unroll
        for (int i = 0; i < 2; ++i) {
            int q  = tid + i * 256;
            int r  = q >> 2;
            int c8 = (q & 3) * 8;
            *(bf16x8*)&sA[r][c8] = *(const bf16x8*)&A[(size_t)(row0 + r) * 2048 + k0 + c8];
        }
        #pragma unroll
        for (int i = 0; i < 4; ++i) {
            int q  = tid + i * 256;
            int r  = q >> 3;
            int c4 = (q & 7) * 4;
            const f32x4 vb = *(const f32x4*)&W[(size_t)(col0 + r) * 2048 + k0 + c4];
            bf16x4 bh;
            #pragma unroll
            for (int j = 0; j < 4; ++j) bh[j] = (__bf16)vb[j];
            *(bf16x4*)&sB[r][c4] = bh;
        }
        __syncthreads();

        bf16x8 a_f[4], b_f[4];
        #pragma unroll
        for (int f = 0; f < 4; ++f) {
            a_f[f] = *(const bf16x8*)&sA[wm + f * 16 + frow][fkoff];
            b_f[f] = *(const bf16x8*)&sB[wn + f * 16 + frow][fkoff];
        }
        #pragma unroll
        for (int fm = 0; fm < 4; ++fm)
            #pragma unroll
            for (int fn = 0; fn < 4; ++fn)
                acc[fm][fn] = __builtin_amdgcn_mfma_f32_16x16x32_bf16(a_f[fm], b_f[fn], acc[fm][fn], 0, 0, 0);
        __syncthreads();
    }

    const int crow = (lane >> 4) * 4;
    const int ccol = lane & 15;
    #pragma unroll
    for (int fm = 0; fm < 4; ++fm)
        #pragma unroll
        for (int fn = 0; fn < 4; ++fn)
            #pragma unroll
            for (int j = 0; j < 4; ++j) {
                int rg = row0 + wm + fm * 16 + crow + j;
                int cg = col0 + wn + fn * 16 + ccol;
                O[(size_t)rg * 1024 + cg] = tanhf(acc[fm][fn][j] + bias[cg]);
            }
}

// ---------------------------------------------------------------------------
extern "C" void kernel_launch(void* const* d_in, const int* in_sizes, int n_in,
                              void* d_out, int out_size, void* d_ws, size_t ws_size,
                              hipStream_t stream)
{
    const float* x     = (const float*)d_in[0];
    const float* W_in  = (const float*)d_in[1];
    const float* b_in  = (const float*)d_in[2];
    const float* leak  = (const float*)d_in[3];
    const float* thr   = (const float*)d_in[4];
    const float* W_out = (const float*)d_in[5];
    const float* b_out = (const float*)d_in[6];

    const size_t NEED = 64ull * 1024 * 1024;  // comb bf16 [16,1024,2048]
    if (ws_size < NEED) return;

    float*  out  = (float*)d_out;   // also I scratch
    __bf16* comb = (__bf16*)d_ws;

    dim3 grid(8, 128);

    gemm1_f32chain_kernel<<<grid, 256, 0, stream>>>(x, W_in, b_in, out);
    hsru_scan_f32_kernel<<<64, 256, 0, stream>>>(out, leak, thr, comb);
    gemm2_kernel<<<grid, 256, 0, stream>>>(comb, W_out, b_out, out);
}